// Round 8
// baseline (858.164 us; speedup 1.0000x reference)
//
#include <hip/hip_runtime.h>

// Problem dims
#define Bn    128
#define Ntok  49
#define CIN   2048
#define Gq    256
#define Dm    768
#define Hh    8
#define HDd   96
#define FFd   2048
#define NCLS  12547
#define DUPn  50

typedef __attribute__((ext_vector_type(8))) short short8;
typedef __attribute__((ext_vector_type(4))) short short4v;
typedef __attribute__((ext_vector_type(4))) float floatx4;

__device__ __forceinline__ unsigned short f2bf(float f) {
  unsigned u = __builtin_bit_cast(unsigned, f);
  u += 0x7fffu + ((u >> 16) & 1u);   // round-to-nearest-even
  return (unsigned short)(u >> 16);
}
__device__ __forceinline__ float bf2f(unsigned short h) {
  return __builtin_bit_cast(float, (unsigned)h << 16);
}

// async global->LDS, 16 B per lane; LDS dest = wave-uniform base + lane*16
__device__ __forceinline__ void gl_lds16(const unsigned short* g, unsigned short* l) {
  __builtin_amdgcn_global_load_lds(
      (__attribute__((address_space(1))) void*)g,
      (__attribute__((address_space(3))) void*)l, 16, 0, 0);
}

// ---------------------------------------------------------------------------
// bf16 GEMM-BT, BK=64: C[M,N] = op(A[M,K] @ Bt[N,K]^T + bias)
// 128x128 tile, 4 waves (2x2), each wave 64x64 as 4x4 of 16x16x32 MFMA,
// two k-substeps per staged BK=64 tile (halves barrier count vs BK=32).
// Requires M%128==0, N%128==0, K%64==0.
// ---------------------------------------------------------------------------
__global__ __launch_bounds__(256)
void gemm_bt(const unsigned short* __restrict__ A,
             const unsigned short* __restrict__ Bt,
             const float* __restrict__ bias,
             unsigned short* __restrict__ C,
             int M, int N, int K, int relu)
{
  __shared__ unsigned short As[128 * 64];   // 16 KB, [m][k]
  __shared__ unsigned short Bs[128 * 64];   // 16 KB, [n][k]

  const int tid  = threadIdx.x;
  const int m0   = blockIdx.y << 7;
  const int n0   = blockIdx.x << 7;
  const int wave = tid >> 6, lane = tid & 63;
  const int wm   = (wave >> 1) << 6;
  const int wn   = (wave & 1) << 6;
  const int l16  = lane & 15, quad = lane >> 4;

  // staging: wave covers 32 rows x 64 cols; 4 issues of 8 rows (1 KB each)
  const int srow = (wave << 5) + (lane >> 3);
  const int scol = (lane & 7) << 3;
  const unsigned short* gA = A  + (size_t)(m0 + srow) * K + scol;
  const unsigned short* gB = Bt + (size_t)(n0 + srow) * K + scol;
  const size_t rstep8 = (size_t)8 * K;
  unsigned short* lA = &As[(wave << 5) * 64];
  unsigned short* lB = &Bs[(wave << 5) * 64];

  floatx4 acc[4][4];
  const floatx4 zero4 = {0.f, 0.f, 0.f, 0.f};
#pragma unroll
  for (int i = 0; i < 4; ++i)
#pragma unroll
    for (int j = 0; j < 4; ++j) acc[i][j] = zero4;

  for (int k0 = 0; k0 < K; k0 += 64) {
#pragma unroll
    for (int p = 0; p < 4; ++p) {
      gl_lds16(gA + k0 + p * rstep8, lA + (p << 9));
      gl_lds16(gB + k0 + p * rstep8, lB + (p << 9));
    }
    __syncthreads();

#pragma unroll
    for (int ks = 0; ks < 2; ++ks) {
      short8 a[4], b[4];
#pragma unroll
      for (int i = 0; i < 4; ++i)
        a[i] = *(const short8*)&As[(wm + (i << 4) + l16) * 64 + (ks << 5) + (quad << 3)];
#pragma unroll
      for (int j = 0; j < 4; ++j)
        b[j] = *(const short8*)&Bs[(wn + (j << 4) + l16) * 64 + (ks << 5) + (quad << 3)];
#pragma unroll
      for (int i = 0; i < 4; ++i)
#pragma unroll
        for (int j = 0; j < 4; ++j)
          acc[i][j] = __builtin_amdgcn_mfma_f32_16x16x32_bf16(a[i], b[j], acc[i][j], 0, 0, 0);
    }
    __syncthreads();
  }

  // epilogue: C/D layout col=lane&15, row=quad*4+reg
#pragma unroll
  for (int j = 0; j < 4; ++j) {
    const int col = n0 + wn + (j << 4) + l16;
    const float bv = bias[col];
#pragma unroll
    for (int i = 0; i < 4; ++i) {
      const int rbase = m0 + wm + (i << 4) + (quad << 2);
#pragma unroll
      for (int r = 0; r < 4; ++r) {
        float v = acc[i][j][r] + bv;
        if (relu) v = fmaxf(v, 0.f);
        C[(size_t)(rbase + r) * N + col] = f2bf(v);
      }
    }
  }
}

// ---------------------------------------------------------------------------
// fp32 -> bf16 elementwise (n multiple of 4)
// ---------------------------------------------------------------------------
__global__ __launch_bounds__(256)
void cvt_k(const float* __restrict__ in, unsigned short* __restrict__ out, int n4)
{
  const int i = blockIdx.x * 256 + threadIdx.x;
  if (i < n4) {
    floatx4 v = ((const floatx4*)in)[i];
    short4v s;
    s.x = (short)f2bf(v.x); s.y = (short)f2bf(v.y);
    s.z = (short)f2bf(v.z); s.w = (short)f2bf(v.w);
    ((short4v*)out)[i] = s;
  }
}

// ---------------------------------------------------------------------------
// Merged weight prep: 7 transpose+convert jobs (fp32 [K][N] -> bf16 [N][K])
// in one dispatch. Descriptor table passed by value; flat grid.
// ---------------------------------------------------------------------------
struct WPrep {
  const float* src[7];
  unsigned short* dst[7];
  int K[7], N[7], nb[7];   // nb = (N/32)*(K/32)
};

__global__ __launch_bounds__(256)
void wprep_k(WPrep p)
{
  __shared__ float tile[32][33];
  int id = blockIdx.x, e = 0, base = 0;
  while (e < 7 && id >= base + p.nb[e]) { base += p.nb[e]; ++e; }
  if (e >= 7) return;
  const int local = id - base;
  const int K = p.K[e], N = p.N[e];
  const int nbx = N >> 5;
  const int nb = (local % nbx) << 5, kb = (local / nbx) << 5;
  const float* in = p.src[e];
  unsigned short* out = p.dst[e];
  const int tx = threadIdx.x & 31, ty = threadIdx.x >> 5;   // 32 x 8
#pragma unroll
  for (int i = 0; i < 4; ++i)
    tile[ty + (i << 3)][tx] = in[(size_t)(kb + ty + (i << 3)) * N + nb + tx];
  __syncthreads();
#pragma unroll
  for (int i = 0; i < 4; ++i)
    out[(size_t)(nb + ty + (i << 3)) * K + kb + tx] = f2bf(tile[tx][ty + (i << 3)]);
}

// ---------------------------------------------------------------------------
// bias concat: bkv[0:768]=bk, bkv[768:1536]=bv
// ---------------------------------------------------------------------------
__global__ __launch_bounds__(256)
void bkv_k(const float* __restrict__ bk, const float* __restrict__ bv,
           float* __restrict__ o)
{
  const int i = blockIdx.x * 256 + threadIdx.x;
  if (i < Dm) o[i] = bk[i];
  else if (i < 2 * Dm) o[i] = bv[i - Dm];
}

// ---------------------------------------------------------------------------
// Wg transpose: fp32 [g][768][50] -> bf16 [g][64][768], f>=50 zero-padded.
// ---------------------------------------------------------------------------
__global__ __launch_bounds__(256)
void wg_trans_k(const float* __restrict__ Wg, unsigned short* __restrict__ out)
{
  __shared__ float tile[32][33];
  const int g  = blockIdx.z;
  const int nb = blockIdx.x << 5, kb = blockIdx.y << 5;
  const int tx = threadIdx.x & 31, ty = threadIdx.x >> 5;
  const float* in = Wg + (size_t)g * Dm * DUPn;
#pragma unroll
  for (int i = 0; i < 4; ++i) {
    const int f = nb + tx;
    tile[ty + (i << 3)][tx] =
        (f < DUPn) ? in[(size_t)(kb + ty + (i << 3)) * DUPn + f] : 0.f;
  }
  __syncthreads();
  unsigned short* o = out + (size_t)g * 64 * Dm;
#pragma unroll
  for (int i = 0; i < 4; ++i)
    o[(size_t)(nb + ty + (i << 3)) * Dm + kb + tx] = f2bf(tile[tx][ty + (i << 3)]);
}

// ---------------------------------------------------------------------------
// GroupFC via MFMA. One block per group g (251). M=128 batch, N=64, K=768.
// ---------------------------------------------------------------------------
__global__ __launch_bounds__(256)
void groupfc_k(const unsigned short* __restrict__ hb, const unsigned short* __restrict__ wgT,
               const float* __restrict__ bg, float* __restrict__ out,
               int b0, int bcnt)
{
  __shared__ unsigned short As[128 * 32];
  __shared__ unsigned short Bs[64 * 32];

  const int g    = blockIdx.x;
  const int tid  = threadIdx.x;
  const int wave = tid >> 6, lane = tid & 63;
  const int wm   = (wave & 1) << 6;
  const int wn   = (wave >> 1) << 5;
  const int l16  = lane & 15, quad = lane >> 4;

  const int srow = (wave << 5) + (lane >> 2);
  const int brow = (wave << 4) + (lane >> 2);
  const int scol = (lane & 3) << 3;
  const unsigned short* gA = hb + ((size_t)srow * Gq + g) * Dm + scol;
  const unsigned short* gB = wgT + (size_t)g * 64 * Dm + (size_t)brow * Dm + scol;
  const size_t rstepA = (size_t)16 * Gq * Dm;
  unsigned short* lA = &As[wave << 10];
  unsigned short* lB = &Bs[wave << 9];

  floatx4 acc[4][2];
  const floatx4 zero4 = {0.f, 0.f, 0.f, 0.f};
#pragma unroll
  for (int i = 0; i < 4; ++i)
#pragma unroll
    for (int j = 0; j < 2; ++j) acc[i][j] = zero4;

  for (int k0 = 0; k0 < Dm; k0 += 32) {
    gl_lds16(gA + k0,          lA);
    gl_lds16(gA + k0 + rstepA, lA + 512);
    gl_lds16(gB + k0,          lB);
    __syncthreads();

    short8 a[4], b[2];
#pragma unroll
    for (int i = 0; i < 4; ++i)
      a[i] = *(const short8*)&As[(wm + (i << 4) + l16) * 32 + (quad << 3)];
#pragma unroll
    for (int j = 0; j < 2; ++j)
      b[j] = *(const short8*)&Bs[(wn + (j << 4) + l16) * 32 + (quad << 3)];
#pragma unroll
    for (int i = 0; i < 4; ++i)
#pragma unroll
      for (int j = 0; j < 2; ++j)
        acc[i][j] = __builtin_amdgcn_mfma_f32_16x16x32_bf16(a[i], b[j], acc[i][j], 0, 0, 0);
    __syncthreads();
  }

#pragma unroll
  for (int j = 0; j < 2; ++j) {
    const int f = wn + (j << 4) + l16;
    const int col = g * DUPn + f;
    const bool okf = (f < DUPn) && (col < NCLS);
    const float bv = okf ? bg[col] : 0.f;
#pragma unroll
    for (int i = 0; i < 4; ++i) {
      const int bb = wm + (i << 4) + (quad << 2);
#pragma unroll
      for (int r = 0; r < 4; ++r) {
        if (okf && bb + r < bcnt)
          out[(size_t)(b0 + bb + r) * NCLS + col] = acc[i][j][r] + bv;
      }
    }
  }
}

// ---------------------------------------------------------------------------
// Step-1 LayerNorm: out[row] = LN(2*query[row]) * g + b. fp32 in, bf16 out.
// ---------------------------------------------------------------------------
__global__ __launch_bounds__(256)
void ln_query_k(const float* __restrict__ query, const float* __restrict__ gamma,
                const float* __restrict__ beta, unsigned short* __restrict__ out)
{
  const unsigned row = blockIdx.x;
  const float* p = query + (size_t)row * Dm;
  const int tid = threadIdx.x;

  float v[3];
#pragma unroll
  for (int i = 0; i < 3; ++i) v[i] = 2.f * p[tid + (i << 8)];

  float s1 = v[0] + v[1] + v[2];
  float s2 = v[0]*v[0] + v[1]*v[1] + v[2]*v[2];
#pragma unroll
  for (int off = 32; off; off >>= 1) {
    s1 += __shfl_down(s1, off, 64);
    s2 += __shfl_down(s2, off, 64);
  }
  __shared__ float r1[4], r2[4];
  const int wave = tid >> 6, lane = tid & 63;
  if (lane == 0) { r1[wave] = s1; r2[wave] = s2; }
  __syncthreads();
  s1 = r1[0] + r1[1] + r1[2] + r1[3];
  s2 = r2[0] + r2[1] + r2[2] + r2[3];
  const float mean = s1 * (1.f / Dm);
  const float var  = s2 * (1.f / Dm) - mean * mean;
  const float inv  = rsqrtf(var + 1e-5f);
#pragma unroll
  for (int i = 0; i < 3; ++i) {
    const int c = tid + (i << 8);
    out[(size_t)row * Dm + c] = f2bf((v[i] - mean) * inv * gamma[c] + beta[c]);
  }
}

// ---------------------------------------------------------------------------
// Residual LayerNorm: out[row] = LN(in1[row] + in2[row & mask]) * g + b.
// ---------------------------------------------------------------------------
__global__ __launch_bounds__(256)
void ln_k(const unsigned short* __restrict__ in1, const unsigned short* __restrict__ in2,
          unsigned in2mask, const float* __restrict__ gamma,
          const float* __restrict__ beta, unsigned short* __restrict__ out)
{
  const unsigned row = blockIdx.x;
  const unsigned short* p1 = in1 + (size_t)row * Dm;
  const unsigned short* p2 = in2 + (size_t)(row & in2mask) * Dm;
  const int tid = threadIdx.x;

  float v[3];
#pragma unroll
  for (int i = 0; i < 3; ++i) v[i] = bf2f(p1[tid + (i << 8)]) + bf2f(p2[tid + (i << 8)]);

  float s1 = v[0] + v[1] + v[2];
  float s2 = v[0]*v[0] + v[1]*v[1] + v[2]*v[2];
#pragma unroll
  for (int off = 32; off; off >>= 1) {
    s1 += __shfl_down(s1, off, 64);
    s2 += __shfl_down(s2, off, 64);
  }
  __shared__ float r1[4], r2[4];
  const int wave = tid >> 6, lane = tid & 63;
  if (lane == 0) { r1[wave] = s1; r2[wave] = s2; }
  __syncthreads();
  s1 = r1[0] + r1[1] + r1[2] + r1[3];
  s2 = r2[0] + r2[1] + r2[2] + r2[3];
  const float mean = s1 * (1.f / Dm);
  const float var  = s2 * (1.f / Dm) - mean * mean;
  const float inv  = rsqrtf(var + 1e-5f);
#pragma unroll
  for (int i = 0; i < 3; ++i) {
    const int c = tid + (i << 8);
    out[(size_t)row * Dm + c] = f2bf((v[i] - mean) * inv * gamma[c] + beta[c]);
  }
}

// ---------------------------------------------------------------------------
// MFMA cross-attention, fused-KV layout: kv[b][n][0:768]=K, [768:1536]=V.
// One block per (head h, chunk-local batch bl).
// ---------------------------------------------------------------------------
__global__ __launch_bounds__(256)
void attn_k(const unsigned short* __restrict__ qall, const unsigned short* __restrict__ kv,
            unsigned short* __restrict__ attno, int b0)
{
  __shared__ unsigned short smem[24576];           // 48 KB
  unsigned short* Vt = smem;                       // [96][64]
  unsigned short* Ks = smem + 6144;                // [64][96] (dead after S)
  unsigned short* Ps = smem + 6144;                // [256][72] (aliases Ks)

  const int h = blockIdx.x, bl = blockIdx.y;
  const int b = b0 + bl;
  const int tid  = threadIdx.x;
  const int wave = tid >> 6, lane = tid & 63;
  const int l16  = lane & 15, quad = lane >> 4;
  const int wm   = wave << 6;

  const size_t kvbase = (size_t)b * Ntok * 1536 + h * HDd;

  // ---- stage K [64][96] (zero-pad n>=49) ----
  for (int s = tid; s < 64 * 12; s += 256) {
    const int n = s / 12, c8 = (s - n * 12) << 3;
    short8 v = {0, 0, 0, 0, 0, 0, 0, 0};
    if (n < Ntok) v = *(const short8*)(kv + kvbase + (size_t)n * 1536 + c8);
    *(short8*)&Ks[n * 96 + c8] = v;
  }
  // ---- stage V^T [96][64] ----
  for (int s = tid; s < Ntok * 12; s += 256) {
    const int n = s / 12, c8 = (s - n * 12) << 3;
    short8 v = *(const short8*)(kv + kvbase + (size_t)n * 1536 + Dm + c8);
#pragma unroll
    for (int j = 0; j < 8; ++j) Vt[(c8 + j) * 64 + n] = v[j];
  }
  for (int s = tid; s < 96 * 15; s += 256) {
    const int d = s / 15, n = Ntok + (s - d * 15);
    Vt[d * 64 + n] = 0;
  }
  __syncthreads();

  // ---- phase 1: S = Q @ K^T ----
  floatx4 acc[4][4];
  const floatx4 zero4 = {0.f, 0.f, 0.f, 0.f};
#pragma unroll
  for (int i = 0; i < 4; ++i)
#pragma unroll
    for (int j = 0; j < 4; ++j) acc[i][j] = zero4;

#pragma unroll
  for (int kk = 0; kk < 96; kk += 32) {
    short8 a[4], bf[4];
#pragma unroll
    for (int i = 0; i < 4; ++i)
      a[i] = *(const short8*)(qall + (size_t)(wm + (i << 4) + l16) * Dm + h * HDd + kk + (quad << 3));
#pragma unroll
    for (int j = 0; j < 4; ++j)
      bf[j] = *(const short8*)&Ks[((j << 4) + l16) * 96 + kk + (quad << 3)];
#pragma unroll
    for (int i = 0; i < 4; ++i)
#pragma unroll
      for (int j = 0; j < 4; ++j)
        acc[i][j] = __builtin_amdgcn_mfma_f32_16x16x32_bf16(a[i], bf[j], acc[i][j], 0, 0, 0);
  }
  __syncthreads();

  // ---- phase 2: softmax; P -> LDS (bf16, A-layout) ----
  const float scale = 0.10206207261596575f;  // 1/sqrt(96)
#pragma unroll
  for (int i = 0; i < 4; ++i) {
#pragma unroll
    for (int r = 0; r < 4; ++r) {
      float s0 = acc[i][0][r], s1 = acc[i][1][r];
      float s2 = acc[i][2][r], s3 = acc[i][3][r];
      if (l16 > 0) s3 = -1e30f;
      float mx = fmaxf(fmaxf(s0, s1), fmaxf(s2, s3));
      mx = fmaxf(mx, __shfl_xor(mx, 1));
      mx = fmaxf(mx, __shfl_xor(mx, 2));
      mx = fmaxf(mx, __shfl_xor(mx, 4));
      mx = fmaxf(mx, __shfl_xor(mx, 8));
      const float e0 = __expf((s0 - mx) * scale);
      const float e1 = __expf((s1 - mx) * scale);
      const float e2 = __expf((s2 - mx) * scale);
      const float e3 = __expf((s3 - mx) * scale);
      float sum = e0 + e1 + e2 + e3;
      sum += __shfl_xor(sum, 1);
      sum += __shfl_xor(sum, 2);
      sum += __shfl_xor(sum, 4);
      sum += __shfl_xor(sum, 8);
      const float rs = 1.f / sum;
      const int m = wm + (i << 4) + (quad << 2) + r;
      Ps[m * 72 +      l16] = f2bf(e0 * rs);
      Ps[m * 72 + 16 + l16] = f2bf(e1 * rs);
      Ps[m * 72 + 32 + l16] = f2bf(e2 * rs);
      Ps[m * 72 + 48 + l16] = f2bf(e3 * rs);
    }
  }
  __syncthreads();

  // ---- phase 3: O = P @ V ----
  floatx4 o[4][6];
#pragma unroll
  for (int i = 0; i < 4; ++i)
#pragma unroll
    for (int j = 0; j < 6; ++j) o[i][j] = zero4;

#pragma unroll
  for (int kk = 0; kk < 64; kk += 32) {
    short8 a[4], bf[6];
#pragma unroll
    for (int i = 0; i < 4; ++i)
      a[i] = *(const short8*)&Ps[(wm + (i << 4) + l16) * 72 + kk + (quad << 3)];
#pragma unroll
    for (int j = 0; j < 6; ++j)
      bf[j] = *(const short8*)&Vt[((j << 4) + l16) * 64 + kk + (quad << 3)];
#pragma unroll
    for (int i = 0; i < 4; ++i)
#pragma unroll
      for (int j = 0; j < 6; ++j)
        o[i][j] = __builtin_amdgcn_mfma_f32_16x16x32_bf16(a[i], bf[j], o[i][j], 0, 0, 0);
  }

#pragma unroll
  for (int j = 0; j < 6; ++j) {
    const int d = (j << 4) + l16;
#pragma unroll
    for (int i = 0; i < 4; ++i) {
      const int mb = wm + (i << 4) + (quad << 2);
#pragma unroll
      for (int r = 0; r < 4; ++r)
        attno[((size_t)bl * Gq + mb + r) * Dm + h * HDd + d] = f2bf(o[i][j][r]);
    }
  }
}

// ---------------------------------------------------------------------------

static inline void gemm_launch(const unsigned short* A, const unsigned short* Bt,
                               const float* bias, unsigned short* C,
                               int M, int N, int K, int relu, hipStream_t s) {
  dim3 grid(N >> 7, M >> 7);
  gemm_bt<<<grid, 256, 0, s>>>(A, Bt, bias, C, M, N, K, relu);
}

extern "C" void kernel_launch(void* const* d_in, const int* in_sizes, int n_in,
                              void* d_out, int out_size, void* d_ws, size_t ws_size,
                              hipStream_t stream) {
  const float* x       = (const float*)d_in[0];
  const float* W_embed = (const float*)d_in[1];
  const float* b_embed = (const float*)d_in[2];
  const float* query   = (const float*)d_in[3];
  const float* Wq = (const float*)d_in[4];  const float* bq  = (const float*)d_in[5];
  const float* Wk = (const float*)d_in[6];  const float* bk  = (const float*)d_in[7];
  const float* Wv = (const float*)d_in[8];  const float* bv  = (const float*)d_in[9];
  const float* Wo = (const float*)d_in[10]; const float* bo  = (const float*)d_in[11];
  const float* g1 = (const float*)d_in[12]; const float* be1 = (const float*)d_in[13];
  const float* g2 = (const float*)d_in[14]; const float* be2 = (const float*)d_in[15];
  const float* g3 = (const float*)d_in[16]; const float* be3 = (const float*)d_in[17];
  const float* W1 = (const float*)d_in[18]; const float* b1  = (const float*)d_in[19];
  const float* W2 = (const float*)d_in[20]; const float* b2  = (const float*)d_in[21];
  const float* Wg = (const float*)d_in[22]; const float* bg  = (const float*)d_in[23];
  float* out = (float*)d_out;              // fp32 logits

  // ---- workspace carve (bf16 elements) ----
  unsigned short* ws    = (unsigned short*)d_ws;
  unsigned short* tbuf  = ws;                    // 256*768
  unsigned short* qall  = tbuf  + 196608;        // 256*768
  unsigned short* mem   = qall  + 196608;        // 6272*768
  unsigned short* kvbuf = mem   + 4816896;       // 6272*1536 (K|V fused)
  unsigned short* xbf   = kvbuf + 9633792;       // 6272*2048; reused as wgT
  unsigned short* wembT = xbf   + 12845056;      // 768*2048
  unsigned short* wqT   = wembT + 1572864;       // 768*768
  unsigned short* wkT   = wqT   + 589824;        // wkT|wvT adjacent => N=1536 Bt
  unsigned short* wvT   = wkT   + 589824;
  unsigned short* woT   = wvT   + 589824;
  unsigned short* w1T   = woT   + 589824;        // 2048*768
  unsigned short* w2T   = w1T   + 1572864;       // 768*2048
  float*          bkv   = (float*)(w2T + 1572864);  // 1536 fp32 (=3072 shorts)
  unsigned short* attc  = w2T   + 1572864 + 3072;   // chunk start
  unsigned short* wgT   = xbf;                   // 251*64*768 = 12337152

  const size_t fixed_elems = 34769920;
  int CB = 128;
  while (CB > 4 && (fixed_elems + (size_t)CB * 1114112) * 2 > ws_size) CB >>= 1;
  const size_t cstride = (size_t)CB * 196608;    // CB*256*768
  unsigned short* oprc = attc + cstride;         // chunk oproj (reused as h)
  unsigned short* t2c  = oprc + cstride;         // chunk t2
  unsigned short* ff1c = t2c  + cstride;         // chunk CB*256*2048
  unsigned short* ff2c = attc;
  unsigned short* hc   = oprc;

  // 0. one-time conversions
  cvt_k<<<(Bn * Ntok * CIN / 4 + 255) / 256, 256, 0, stream>>>(x, xbf, Bn * Ntok * CIN / 4);
  {
    WPrep p;
    p.src[0] = W_embed; p.dst[0] = wembT; p.K[0] = CIN; p.N[0] = Dm;
    p.src[1] = Wq;      p.dst[1] = wqT;   p.K[1] = Dm;  p.N[1] = Dm;
    p.src[2] = Wk;      p.dst[2] = wkT;   p.K[2] = Dm;  p.N[2] = Dm;
    p.src[3] = Wv;      p.dst[3] = wvT;   p.K[3] = Dm;  p.N[3] = Dm;
    p.src[4] = Wo;      p.dst[4] = woT;   p.K[4] = Dm;  p.N[4] = Dm;
    p.src[5] = W1;      p.dst[5] = w1T;   p.K[5] = Dm;  p.N[5] = FFd;
    p.src[6] = W2;      p.dst[6] = w2T;   p.K[6] = FFd; p.N[6] = Dm;
    int total = 0;
    for (int e = 0; e < 7; ++e) { p.nb[e] = (p.N[e] >> 5) * (p.K[e] >> 5); total += p.nb[e]; }
    wprep_k<<<total, 256, 0, stream>>>(p);
  }
  bkv_k<<<6, 256, 0, stream>>>(bk, bv, bkv);

  // 1. t = LN(2*query)                  [batch-independent]
  ln_query_k<<<Gq, 256, 0, stream>>>(query, g1, be1, tbuf);
  // 2. qall = t @ Wq + bq               [batch-independent]
  gemm_launch(tbuf, wqT, bq, qall, Gq, Dm, Dm, 0, stream);
  // 3. mem = relu(x @ W_embed + b_embed)   (last read of xbf)
  gemm_launch(xbf, wembT, b_embed, mem, Bn * Ntok, Dm, CIN, 1, stream);
  // 3b. Wg -> bf16 [g][64][768] into the now-dead xbf region
  wg_trans_k<<<dim3(2, Dm / 32, 251), 256, 0, stream>>>(Wg, wgT);
  // 4. fused K|V projection: [6272][1536]
  gemm_launch(mem, wkT, bkv, kvbuf, Bn * Ntok, 2 * Dm, Dm, 0, stream);

  // ---- decoder tail, chunked over batch ----
  for (int b0 = 0; b0 < Bn; b0 += CB) {
    const int rows = CB * Gq;
    attn_k<<<dim3(Hh, CB), 256, 0, stream>>>(qall, kvbuf, attc, b0);
    gemm_launch(attc, woT, bo, oprc, rows, Dm, Dm, 0, stream);
    ln_k<<<rows, 256, 0, stream>>>(oprc, tbuf, 255u, g2, be2, t2c);
    gemm_launch(t2c, w1T, b1, ff1c, rows, FFd, Dm, 1, stream);
    gemm_launch(ff1c, w2T, b2, ff2c, rows, Dm, FFd, 0, stream);
    ln_k<<<rows, 256, 0, stream>>>(ff2c, t2c, 0xFFFFFFFFu, g3, be3, hc);
    groupfc_k<<<251, 256, 0, stream>>>(hc, wgT, bg, out, b0, CB);
  }
}

// Round 9
// 769.683 us; speedup vs baseline: 1.1150x; 1.1150x over previous
//
#include <hip/hip_runtime.h>

// Problem dims
#define Bn    128
#define Ntok  49
#define CIN   2048
#define Gq    256
#define Dm    768
#define Hh    8
#define HDd   96
#define FFd   2048
#define NCLS  12547
#define DUPn  50

typedef __attribute__((ext_vector_type(8))) short short8;
typedef __attribute__((ext_vector_type(4))) short short4v;
typedef __attribute__((ext_vector_type(4))) float floatx4;

__device__ __forceinline__ unsigned short f2bf(float f) {
  unsigned u = __builtin_bit_cast(unsigned, f);
  u += 0x7fffu + ((u >> 16) & 1u);   // round-to-nearest-even
  return (unsigned short)(u >> 16);
}
__device__ __forceinline__ float bf2f(unsigned short h) {
  return __builtin_bit_cast(float, (unsigned)h << 16);
}

// async global->LDS, 16 B per lane; LDS dest = wave-uniform base + lane*16
__device__ __forceinline__ void gl_lds16(const unsigned short* g, unsigned short* l) {
  __builtin_amdgcn_global_load_lds(
      (__attribute__((address_space(1))) void*)g,
      (__attribute__((address_space(3))) void*)l, 16, 0, 0);
}

// ---------------------------------------------------------------------------
// m97-style bf16 GEMM-BT, BK=32 + L2 group swizzle.
// C[M,N] = op(A[M,K] @ Bt[N,K]^T + bias). 1D grid gx*gy; 16 m-rows per
// group, n fastest within a group -> A block-row reused across n from L2.
// ---------------------------------------------------------------------------
__global__ __launch_bounds__(256)
void gemm_bt(const unsigned short* __restrict__ A,
             const unsigned short* __restrict__ Bt,
             const float* __restrict__ bias,
             unsigned short* __restrict__ C,
             int N, int K, int relu, int gx, int gy)
{
  __shared__ unsigned short As[128 * 32];
  __shared__ unsigned short Bs[128 * 32];

  // ---- group swizzle: 16 m-rows per group, n fastest ----
  const int bid = blockIdx.x;
  const int nig = gx << 4;
  const int grp = bid / nig;
  const int rem = bid - grp * nig;
  const int base_m = grp << 4;
  int mrows = gy - base_m; if (mrows > 16) mrows = 16;
  const int m0 = (base_m + rem % mrows) << 7;
  const int n0 = (rem / mrows) << 7;

  const int tid  = threadIdx.x;
  const int wave = tid >> 6, lane = tid & 63;
  const int wm   = (wave >> 1) << 6;
  const int wn   = (wave & 1) << 6;
  const int l16  = lane & 15, quad = lane >> 4;

  const int srow = (wave << 5) + (lane >> 2);
  const int scol = (lane & 3) << 3;
  const unsigned short* gA = A  + (size_t)(m0 + srow) * K + scol;
  const unsigned short* gB = Bt + (size_t)(n0 + srow) * K + scol;
  const size_t rstep = (size_t)16 * K;
  unsigned short* lA = &As[wave << 10];
  unsigned short* lB = &Bs[wave << 10];

  floatx4 acc[4][4];
  const floatx4 zero4 = {0.f, 0.f, 0.f, 0.f};
#pragma unroll
  for (int i = 0; i < 4; ++i)
#pragma unroll
    for (int j = 0; j < 4; ++j) acc[i][j] = zero4;

  for (int k0 = 0; k0 < K; k0 += 32) {
    gl_lds16(gA + k0,         lA);
    gl_lds16(gA + k0 + rstep, lA + 512);
    gl_lds16(gB + k0,         lB);
    gl_lds16(gB + k0 + rstep, lB + 512);
    __syncthreads();

    short8 a[4], b[4];
#pragma unroll
    for (int i = 0; i < 4; ++i)
      a[i] = *(const short8*)&As[(wm + (i << 4) + l16) * 32 + (quad << 3)];
#pragma unroll
    for (int j = 0; j < 4; ++j)
      b[j] = *(const short8*)&Bs[(wn + (j << 4) + l16) * 32 + (quad << 3)];
#pragma unroll
    for (int i = 0; i < 4; ++i)
#pragma unroll
      for (int j = 0; j < 4; ++j)
        acc[i][j] = __builtin_amdgcn_mfma_f32_16x16x32_bf16(a[i], b[j], acc[i][j], 0, 0, 0);
    __syncthreads();
  }

  // epilogue: C/D layout col=lane&15, row=quad*4+reg
#pragma unroll
  for (int j = 0; j < 4; ++j) {
    const int col = n0 + wn + (j << 4) + l16;
    const float bv = bias[col];
#pragma unroll
    for (int i = 0; i < 4; ++i) {
      const int rbase = m0 + wm + (i << 4) + (quad << 2);
#pragma unroll
      for (int r = 0; r < 4; ++r) {
        float v = acc[i][j][r] + bv;
        if (relu) v = fmaxf(v, 0.f);
        C[(size_t)(rbase + r) * N + col] = f2bf(v);
      }
    }
  }
}

// ---------------------------------------------------------------------------
// fp32 -> bf16 elementwise (n multiple of 4)
// ---------------------------------------------------------------------------
__global__ __launch_bounds__(256)
void cvt_k(const float* __restrict__ in, unsigned short* __restrict__ out, int n4)
{
  const int i = blockIdx.x * 256 + threadIdx.x;
  if (i < n4) {
    floatx4 v = ((const floatx4*)in)[i];
    short4v s;
    s.x = (short)f2bf(v.x); s.y = (short)f2bf(v.y);
    s.z = (short)f2bf(v.z); s.w = (short)f2bf(v.w);
    ((short4v*)out)[i] = s;
  }
}

// ---------------------------------------------------------------------------
// Merged weight prep: 7 transpose+convert jobs (fp32 [K][N] -> bf16 [N][K]).
// ---------------------------------------------------------------------------
struct WPrep {
  const float* src[7];
  unsigned short* dst[7];
  int K[7], N[7], nb[7];
};

__global__ __launch_bounds__(256)
void wprep_k(WPrep p)
{
  __shared__ float tile[32][33];
  int id = blockIdx.x, e = 0, base = 0;
  while (e < 7 && id >= base + p.nb[e]) { base += p.nb[e]; ++e; }
  if (e >= 7) return;
  const int local = id - base;
  const int K = p.K[e], N = p.N[e];
  const int nbx = N >> 5;
  const int nb = (local % nbx) << 5, kb = (local / nbx) << 5;
  const float* in = p.src[e];
  unsigned short* out = p.dst[e];
  const int tx = threadIdx.x & 31, ty = threadIdx.x >> 5;
#pragma unroll
  for (int i = 0; i < 4; ++i)
    tile[ty + (i << 3)][tx] = in[(size_t)(kb + ty + (i << 3)) * N + nb + tx];
  __syncthreads();
#pragma unroll
  for (int i = 0; i < 4; ++i)
    out[(size_t)(nb + ty + (i << 3)) * K + kb + tx] = f2bf(tile[tx][ty + (i << 3)]);
}

// ---------------------------------------------------------------------------
// bias concat: bkv[0:768]=bk, bkv[768:1536]=bv
// ---------------------------------------------------------------------------
__global__ __launch_bounds__(256)
void bkv_k(const float* __restrict__ bk, const float* __restrict__ bv,
           float* __restrict__ o)
{
  const int i = blockIdx.x * 256 + threadIdx.x;
  if (i < Dm) o[i] = bk[i];
  else if (i < 2 * Dm) o[i] = bv[i - Dm];
}

// ---------------------------------------------------------------------------
// Wg transpose: fp32 [g][768][50] -> bf16 [g][64][768], f>=50 zero-padded.
// ---------------------------------------------------------------------------
__global__ __launch_bounds__(256)
void wg_trans_k(const float* __restrict__ Wg, unsigned short* __restrict__ out)
{
  __shared__ float tile[32][33];
  const int g  = blockIdx.z;
  const int nb = blockIdx.x << 5, kb = blockIdx.y << 5;
  const int tx = threadIdx.x & 31, ty = threadIdx.x >> 5;
  const float* in = Wg + (size_t)g * Dm * DUPn;
#pragma unroll
  for (int i = 0; i < 4; ++i) {
    const int f = nb + tx;
    tile[ty + (i << 3)][tx] =
        (f < DUPn) ? in[(size_t)(kb + ty + (i << 3)) * DUPn + f] : 0.f;
  }
  __syncthreads();
  unsigned short* o = out + (size_t)g * 64 * Dm;
#pragma unroll
  for (int i = 0; i < 4; ++i)
    o[(size_t)(nb + ty + (i << 3)) * Dm + kb + tx] = f2bf(tile[tx][ty + (i << 3)]);
}

// ---------------------------------------------------------------------------
// GroupFC via MFMA. One block per group g (251). M=128 batch, N=64, K=768.
// ---------------------------------------------------------------------------
__global__ __launch_bounds__(256)
void groupfc_k(const unsigned short* __restrict__ hb, const unsigned short* __restrict__ wgT,
               const float* __restrict__ bg, float* __restrict__ out,
               int b0, int bcnt)
{
  __shared__ unsigned short As[128 * 32];
  __shared__ unsigned short Bs[64 * 32];

  const int g    = blockIdx.x;
  const int tid  = threadIdx.x;
  const int wave = tid >> 6, lane = tid & 63;
  const int wm   = (wave & 1) << 6;
  const int wn   = (wave >> 1) << 5;
  const int l16  = lane & 15, quad = lane >> 4;

  const int srow = (wave << 5) + (lane >> 2);
  const int brow = (wave << 4) + (lane >> 2);
  const int scol = (lane & 3) << 3;
  const unsigned short* gA = hb + ((size_t)srow * Gq + g) * Dm + scol;
  const unsigned short* gB = wgT + (size_t)g * 64 * Dm + (size_t)brow * Dm + scol;
  const size_t rstepA = (size_t)16 * Gq * Dm;
  unsigned short* lA = &As[wave << 10];
  unsigned short* lB = &Bs[wave << 9];

  floatx4 acc[4][2];
  const floatx4 zero4 = {0.f, 0.f, 0.f, 0.f};
#pragma unroll
  for (int i = 0; i < 4; ++i)
#pragma unroll
    for (int j = 0; j < 2; ++j) acc[i][j] = zero4;

  for (int k0 = 0; k0 < Dm; k0 += 32) {
    gl_lds16(gA + k0,          lA);
    gl_lds16(gA + k0 + rstepA, lA + 512);
    gl_lds16(gB + k0,          lB);
    __syncthreads();

    short8 a[4], b[2];
#pragma unroll
    for (int i = 0; i < 4; ++i)
      a[i] = *(const short8*)&As[(wm + (i << 4) + l16) * 32 + (quad << 3)];
#pragma unroll
    for (int j = 0; j < 2; ++j)
      b[j] = *(const short8*)&Bs[(wn + (j << 4) + l16) * 32 + (quad << 3)];
#pragma unroll
    for (int i = 0; i < 4; ++i)
#pragma unroll
      for (int j = 0; j < 2; ++j)
        acc[i][j] = __builtin_amdgcn_mfma_f32_16x16x32_bf16(a[i], b[j], acc[i][j], 0, 0, 0);
    __syncthreads();
  }

#pragma unroll
  for (int j = 0; j < 2; ++j) {
    const int f = wn + (j << 4) + l16;
    const int col = g * DUPn + f;
    const bool okf = (f < DUPn) && (col < NCLS);
    const float bv = okf ? bg[col] : 0.f;
#pragma unroll
    for (int i = 0; i < 4; ++i) {
      const int bb = wm + (i << 4) + (quad << 2);
#pragma unroll
      for (int r = 0; r < 4; ++r) {
        if (okf && bb + r < bcnt)
          out[(size_t)(b0 + bb + r) * NCLS + col] = acc[i][j][r] + bv;
      }
    }
  }
}

// ---------------------------------------------------------------------------
// Step-1 LayerNorm: out[row] = LN(2*query[row]) * g + b. fp32 in, bf16 out.
// ---------------------------------------------------------------------------
__global__ __launch_bounds__(256)
void ln_query_k(const float* __restrict__ query, const float* __restrict__ gamma,
                const float* __restrict__ beta, unsigned short* __restrict__ out)
{
  const unsigned row = blockIdx.x;
  const float* p = query + (size_t)row * Dm;
  const int tid = threadIdx.x;

  float v[3];
#pragma unroll
  for (int i = 0; i < 3; ++i) v[i] = 2.f * p[tid + (i << 8)];

  float s1 = v[0] + v[1] + v[2];
  float s2 = v[0]*v[0] + v[1]*v[1] + v[2]*v[2];
#pragma unroll
  for (int off = 32; off; off >>= 1) {
    s1 += __shfl_down(s1, off, 64);
    s2 += __shfl_down(s2, off, 64);
  }
  __shared__ float r1[4], r2[4];
  const int wave = tid >> 6, lane = tid & 63;
  if (lane == 0) { r1[wave] = s1; r2[wave] = s2; }
  __syncthreads();
  s1 = r1[0] + r1[1] + r1[2] + r1[3];
  s2 = r2[0] + r2[1] + r2[2] + r2[3];
  const float mean = s1 * (1.f / Dm);
  const float var  = s2 * (1.f / Dm) - mean * mean;
  const float inv  = rsqrtf(var + 1e-5f);
#pragma unroll
  for (int i = 0; i < 3; ++i) {
    const int c = tid + (i << 8);
    out[(size_t)row * Dm + c] = f2bf((v[i] - mean) * inv * gamma[c] + beta[c]);
  }
}

// ---------------------------------------------------------------------------
// Residual LayerNorm: out[row] = LN(in1[row] + in2[row & mask]) * g + b.
// ---------------------------------------------------------------------------
__global__ __launch_bounds__(256)
void ln_k(const unsigned short* __restrict__ in1, const unsigned short* __restrict__ in2,
          unsigned in2mask, const float* __restrict__ gamma,
          const float* __restrict__ beta, unsigned short* __restrict__ out)
{
  const unsigned row = blockIdx.x;
  const unsigned short* p1 = in1 + (size_t)row * Dm;
  const unsigned short* p2 = in2 + (size_t)(row & in2mask) * Dm;
  const int tid = threadIdx.x;

  float v[3];
#pragma unroll
  for (int i = 0; i < 3; ++i) v[i] = bf2f(p1[tid + (i << 8)]) + bf2f(p2[tid + (i << 8)]);

  float s1 = v[0] + v[1] + v[2];
  float s2 = v[0]*v[0] + v[1]*v[1] + v[2]*v[2];
#pragma unroll
  for (int off = 32; off; off >>= 1) {
    s1 += __shfl_down(s1, off, 64);
    s2 += __shfl_down(s2, off, 64);
  }
  __shared__ float r1[4], r2[4];
  const int wave = tid >> 6, lane = tid & 63;
  if (lane == 0) { r1[wave] = s1; r2[wave] = s2; }
  __syncthreads();
  s1 = r1[0] + r1[1] + r1[2] + r1[3];
  s2 = r2[0] + r2[1] + r2[2] + r2[3];
  const float mean = s1 * (1.f / Dm);
  const float var  = s2 * (1.f / Dm) - mean * mean;
  const float inv  = rsqrtf(var + 1e-5f);
#pragma unroll
  for (int i = 0; i < 3; ++i) {
    const int c = tid + (i << 8);
    out[(size_t)row * Dm + c] = f2bf((v[i] - mean) * inv * gamma[c] + beta[c]);
  }
}

// ---------------------------------------------------------------------------
// MFMA cross-attention, fused-KV layout: kv[b][n][0:768]=K, [768:1536]=V.
// ---------------------------------------------------------------------------
__global__ __launch_bounds__(256)
void attn_k(const unsigned short* __restrict__ qall, const unsigned short* __restrict__ kv,
            unsigned short* __restrict__ attno, int b0)
{
  __shared__ unsigned short smem[24576];           // 48 KB
  unsigned short* Vt = smem;                       // [96][64]
  unsigned short* Ks = smem + 6144;                // [64][96]
  unsigned short* Ps = smem + 6144;                // [256][72] (aliases Ks)

  const int h = blockIdx.x, bl = blockIdx.y;
  const int b = b0 + bl;
  const int tid  = threadIdx.x;
  const int wave = tid >> 6, lane = tid & 63;
  const int l16  = lane & 15, quad = lane >> 4;
  const int wm   = wave << 6;

  const size_t kvbase = (size_t)b * Ntok * 1536 + h * HDd;

  for (int s = tid; s < 64 * 12; s += 256) {
    const int n = s / 12, c8 = (s - n * 12) << 3;
    short8 v = {0, 0, 0, 0, 0, 0, 0, 0};
    if (n < Ntok) v = *(const short8*)(kv + kvbase + (size_t)n * 1536 + c8);
    *(short8*)&Ks[n * 96 + c8] = v;
  }
  for (int s = tid; s < Ntok * 12; s += 256) {
    const int n = s / 12, c8 = (s - n * 12) << 3;
    short8 v = *(const short8*)(kv + kvbase + (size_t)n * 1536 + Dm + c8);
#pragma unroll
    for (int j = 0; j < 8; ++j) Vt[(c8 + j) * 64 + n] = v[j];
  }
  for (int s = tid; s < 96 * 15; s += 256) {
    const int d = s / 15, n = Ntok + (s - d * 15);
    Vt[d * 64 + n] = 0;
  }
  __syncthreads();

  floatx4 acc[4][4];
  const floatx4 zero4 = {0.f, 0.f, 0.f, 0.f};
#pragma unroll
  for (int i = 0; i < 4; ++i)
#pragma unroll
    for (int j = 0; j < 4; ++j) acc[i][j] = zero4;

#pragma unroll
  for (int kk = 0; kk < 96; kk += 32) {
    short8 a[4], bf[4];
#pragma unroll
    for (int i = 0; i < 4; ++i)
      a[i] = *(const short8*)(qall + (size_t)(wm + (i << 4) + l16) * Dm + h * HDd + kk + (quad << 3));
#pragma unroll
    for (int j = 0; j < 4; ++j)
      bf[j] = *(const short8*)&Ks[((j << 4) + l16) * 96 + kk + (quad << 3)];
#pragma unroll
    for (int i = 0; i < 4; ++i)
#pragma unroll
      for (int j = 0; j < 4; ++j)
        acc[i][j] = __builtin_amdgcn_mfma_f32_16x16x32_bf16(a[i], bf[j], acc[i][j], 0, 0, 0);
  }
  __syncthreads();

  const float scale = 0.10206207261596575f;  // 1/sqrt(96)
#pragma unroll
  for (int i = 0; i < 4; ++i) {
#pragma unroll
    for (int r = 0; r < 4; ++r) {
      float s0 = acc[i][0][r], s1 = acc[i][1][r];
      float s2 = acc[i][2][r], s3 = acc[i][3][r];
      if (l16 > 0) s3 = -1e30f;
      float mx = fmaxf(fmaxf(s0, s1), fmaxf(s2, s3));
      mx = fmaxf(mx, __shfl_xor(mx, 1));
      mx = fmaxf(mx, __shfl_xor(mx, 2));
      mx = fmaxf(mx, __shfl_xor(mx, 4));
      mx = fmaxf(mx, __shfl_xor(mx, 8));
      const float e0 = __expf((s0 - mx) * scale);
      const float e1 = __expf((s1 - mx) * scale);
      const float e2 = __expf((s2 - mx) * scale);
      const float e3 = __expf((s3 - mx) * scale);
      float sum = e0 + e1 + e2 + e3;
      sum += __shfl_xor(sum, 1);
      sum += __shfl_xor(sum, 2);
      sum += __shfl_xor(sum, 4);
      sum += __shfl_xor(sum, 8);
      const float rs = 1.f / sum;
      const int m = wm + (i << 4) + (quad << 2) + r;
      Ps[m * 72 +      l16] = f2bf(e0 * rs);
      Ps[m * 72 + 16 + l16] = f2bf(e1 * rs);
      Ps[m * 72 + 32 + l16] = f2bf(e2 * rs);
      Ps[m * 72 + 48 + l16] = f2bf(e3 * rs);
    }
  }
  __syncthreads();

  floatx4 o[4][6];
#pragma unroll
  for (int i = 0; i < 4; ++i)
#pragma unroll
    for (int j = 0; j < 6; ++j) o[i][j] = zero4;

#pragma unroll
  for (int kk = 0; kk < 64; kk += 32) {
    short8 a[4], bf[6];
#pragma unroll
    for (int i = 0; i < 4; ++i)
      a[i] = *(const short8*)&Ps[(wm + (i << 4) + l16) * 72 + kk + (quad << 3)];
#pragma unroll
    for (int j = 0; j < 6; ++j)
      bf[j] = *(const short8*)&Vt[((j << 4) + l16) * 64 + kk + (quad << 3)];
#pragma unroll
    for (int i = 0; i < 4; ++i)
#pragma unroll
      for (int j = 0; j < 6; ++j)
        o[i][j] = __builtin_amdgcn_mfma_f32_16x16x32_bf16(a[i], bf[j], o[i][j], 0, 0, 0);
  }

#pragma unroll
  for (int j = 0; j < 6; ++j) {
    const int d = (j << 4) + l16;
#pragma unroll
    for (int i = 0; i < 4; ++i) {
      const int mb = wm + (i << 4) + (quad << 2);
#pragma unroll
      for (int r = 0; r < 4; ++r)
        attno[((size_t)bl * Gq + mb + r) * Dm + h * HDd + d] = f2bf(o[i][j][r]);
    }
  }
}

// ---------------------------------------------------------------------------

static inline void gemm_launch(const unsigned short* A, const unsigned short* Bt,
                               const float* bias, unsigned short* C,
                               int M, int N, int K, int relu, hipStream_t s) {
  const int gx = N >> 7, gy = M >> 7;
  gemm_bt<<<gx * gy, 256, 0, s>>>(A, Bt, bias, C, N, K, relu, gx, gy);
}

extern "C" void kernel_launch(void* const* d_in, const int* in_sizes, int n_in,
                              void* d_out, int out_size, void* d_ws, size_t ws_size,
                              hipStream_t stream) {
  const float* x       = (const float*)d_in[0];
  const float* W_embed = (const float*)d_in[1];
  const float* b_embed = (const float*)d_in[2];
  const float* query   = (const float*)d_in[3];
  const float* Wq = (const float*)d_in[4];  const float* bq  = (const float*)d_in[5];
  const float* Wk = (const float*)d_in[6];  const float* bk  = (const float*)d_in[7];
  const float* Wv = (const float*)d_in[8];  const float* bv  = (const float*)d_in[9];
  const float* Wo = (const float*)d_in[10]; const float* bo  = (const float*)d_in[11];
  const float* g1 = (const float*)d_in[12]; const float* be1 = (const float*)d_in[13];
  const float* g2 = (const float*)d_in[14]; const float* be2 = (const float*)d_in[15];
  const float* g3 = (const float*)d_in[16]; const float* be3 = (const float*)d_in[17];
  const float* W1 = (const float*)d_in[18]; const float* b1  = (const float*)d_in[19];
  const float* W2 = (const float*)d_in[20]; const float* b2  = (const float*)d_in[21];
  const float* Wg = (const float*)d_in[22]; const float* bg  = (const float*)d_in[23];
  float* out = (float*)d_out;              // fp32 logits

  // ---- workspace carve (bf16 elements) ----
  unsigned short* ws    = (unsigned short*)d_ws;
  unsigned short* tbuf  = ws;                    // 256*768
  unsigned short* qall  = tbuf  + 196608;        // 256*768
  unsigned short* mem   = qall  + 196608;        // 6272*768
  unsigned short* kvbuf = mem   + 4816896;       // 6272*1536 (K|V fused)
  unsigned short* xbf   = kvbuf + 9633792;       // 6272*2048; reused as wgT
  unsigned short* wembT = xbf   + 12845056;      // 768*2048
  unsigned short* wqT   = wembT + 1572864;       // 768*768
  unsigned short* wkT   = wqT   + 589824;        // wkT|wvT adjacent => N=1536 Bt
  unsigned short* wvT   = wkT   + 589824;
  unsigned short* woT   = wvT   + 589824;
  unsigned short* w1T   = woT   + 589824;        // 2048*768
  unsigned short* w2T   = w1T   + 1572864;       // 768*2048
  float*          bkv   = (float*)(w2T + 1572864);  // 1536 fp32 (=3072 shorts)
  unsigned short* attc  = w2T   + 1572864 + 3072;   // chunk start
  unsigned short* wgT   = xbf;                   // 251*64*768 = 12337152

  const size_t fixed_elems = 34769920;
  int CB = 128;
  while (CB > 4 && (fixed_elems + (size_t)CB * 1114112) * 2 > ws_size) CB >>= 1;
  const size_t cstride = (size_t)CB * 196608;    // CB*256*768
  unsigned short* oprc = attc + cstride;         // chunk oproj (reused as h)
  unsigned short* t2c  = oprc + cstride;         // chunk t2
  unsigned short* ff1c = t2c  + cstride;         // chunk CB*256*2048
  unsigned short* ff2c = attc;
  unsigned short* hc   = oprc;

  // 0. one-time conversions
  cvt_k<<<(Bn * Ntok * CIN / 4 + 255) / 256, 256, 0, stream>>>(x, xbf, Bn * Ntok * CIN / 4);
  {
    WPrep p;
    p.src[0] = W_embed; p.dst[0] = wembT; p.K[0] = CIN; p.N[0] = Dm;
    p.src[1] = Wq;      p.dst[1] = wqT;   p.K[1] = Dm;  p.N[1] = Dm;
    p.src[2] = Wk;      p.dst[2] = wkT;   p.K[2] = Dm;  p.N[2] = Dm;
    p.src[3] = Wv;      p.dst[3] = wvT;   p.K[3] = Dm;  p.N[3] = Dm;
    p.src[4] = Wo;      p.dst[4] = woT;   p.K[4] = Dm;  p.N[4] = Dm;
    p.src[5] = W1;      p.dst[5] = w1T;   p.K[5] = Dm;  p.N[5] = FFd;
    p.src[6] = W2;      p.dst[6] = w2T;   p.K[6] = FFd; p.N[6] = Dm;
    int total = 0;
    for (int e = 0; e < 7; ++e) { p.nb[e] = (p.N[e] >> 5) * (p.K[e] >> 5); total += p.nb[e]; }
    wprep_k<<<total, 256, 0, stream>>>(p);
  }
  bkv_k<<<6, 256, 0, stream>>>(bk, bv, bkv);

  // 1. t = LN(2*query)                  [batch-independent]
  ln_query_k<<<Gq, 256, 0, stream>>>(query, g1, be1, tbuf);
  // 2. qall = t @ Wq + bq               [batch-independent]
  gemm_launch(tbuf, wqT, bq, qall, Gq, Dm, Dm, 0, stream);
  // 3. mem = relu(x @ W_embed + b_embed)   (last read of xbf)
  gemm_launch(xbf, wembT, b_embed, mem, Bn * Ntok, Dm, CIN, 1, stream);
  // 3b. Wg -> bf16 [g][64][768] into the now-dead xbf region
  wg_trans_k<<<dim3(2, Dm / 32, 251), 256, 0, stream>>>(Wg, wgT);
  // 4. fused K|V projection: [6272][1536]
  gemm_launch(mem, wkT, bkv, kvbuf, Bn * Ntok, 2 * Dm, Dm, 0, stream);

  // ---- decoder tail, chunked over batch ----
  for (int b0 = 0; b0 < Bn; b0 += CB) {
    const int rows = CB * Gq;
    attn_k<<<dim3(Hh, CB), 256, 0, stream>>>(qall, kvbuf, attc, b0);
    gemm_launch(attc, woT, bo, oprc, rows, Dm, Dm, 0, stream);
    ln_k<<<rows, 256, 0, stream>>>(oprc, tbuf, 255u, g2, be2, t2c);
    gemm_launch(t2c, w1T, b1, ff1c, rows, FFd, Dm, 1, stream);
    gemm_launch(ff1c, w2T, b2, ff2c, rows, Dm, FFd, 0, stream);
    ln_k<<<rows, 256, 0, stream>>>(ff2c, t2c, 0xFFFFFFFFu, g3, be3, hc);
    groupfc_k<<<251, 256, 0, stream>>>(hc, wgT, bg, out, b0, CB);
  }
}